// Round 3
// baseline (788.509 us; speedup 1.0000x reference)
//
#include <hip/hip_runtime.h>

typedef short bf16x8 __attribute__((ext_vector_type(8)));
typedef float f32x4  __attribute__((ext_vector_type(4)));

__device__ __forceinline__ unsigned short f2b(float f){
  union { float f; unsigned u; } v; v.f = f;
  unsigned r = v.u + 0x7FFFu + ((v.u >> 16) & 1u);
  return (unsigned short)(r >> 16);
}
__device__ __forceinline__ float b2f(unsigned short s){
  union { unsigned u; float f; } v; v.u = ((unsigned)s) << 16;
  return v.f;
}
// pack two f32 -> one u32 of 2x bf16 (RNE) in one VALU op
__device__ __forceinline__ unsigned pk2(float lo, float hi){
  unsigned r;
  asm("v_cvt_pk_bf16_f32 %0, %1, %2" : "=v"(r) : "v"(lo), "v"(hi));
  return r;
}

// ---------------- stage 1: Qm/Km/Vm = FE @ W_in^T  (3 x 64 x 256) ----------------
__global__ void k_pre_qkv(const float* __restrict__ FE, const float* __restrict__ W_in,
                          float* __restrict__ Qm, float* __restrict__ Km, float* __restrict__ Vm){
  int id = blockIdx.x*256 + threadIdx.x;      // 49152
  int part = id >> 14;
  int l = (id >> 8) & 63;
  int d = id & 255;
  const float4* fe = (const float4*)(FE + l*256);
  const float4* wr = (const float4*)(W_in + (part*256 + d)*256);
  float s = 0.f;
  #pragma unroll 8
  for (int k=0;k<64;k++){
    float4 a = fe[k], b = wr[k];
    s += a.x*b.x + a.y*b.y + a.z*b.z + a.w*b.w;
  }
  float* dst = (part==0)?Qm:((part==1)?Km:Vm);
  dst[l*256+d] = s;
}

// ---------------- stage 2 (merged): att-tables + M2t + weight cvt + RNN ----------------
__global__ void k_pre2(const float* __restrict__ Qm, const float* __restrict__ Km,
                       const float* __restrict__ Vm,
                       const float* __restrict__ b_in, const float* __restrict__ W_ao,
                       const float* __restrict__ b_ao,
                       float* __restrict__ G, float* __restrict__ U,
                       float* __restrict__ W, float* __restrict__ S,
                       float* __restrict__ abias, short* __restrict__ M2t,
                       const float* __restrict__ W1, const float* __restrict__ W2,
                       short* __restrict__ W1b, short* __restrict__ W2b,
                       const float* __restrict__ x_cont, const float* __restrict__ z0,
                       const float* __restrict__ W_ih, const float* __restrict__ W_hh,
                       const float* __restrict__ b_ih, const float* __restrict__ b_hh,
                       const float* __restrict__ Uf, const float* __restrict__ Wfp,
                       const float* __restrict__ bfp, float* __restrict__ zout){
  int bid = blockIdx.x;
  int tid = threadIdx.x;
  if (bid < 134){
    int id = bid*256 + tid;
    const float inv = 0.17677669529663687f;   // 1/sqrt(32)
    if (id < 32768){
      int h = id >> 12, lq = (id>>6)&63, lk = id&63;
      const float* qp = Qm + lq*256 + h*32;
      const float* kp = Km + lk*256 + h*32;
      float s=0.f;
      #pragma unroll
      for (int d=0;d<32;d++) s += qp[d]*kp[d];
      G[id] = s*inv;
    } else if (id < 33280){
      int j = id - 32768; int h = j>>6, lq = j&63;
      const float* qp = Qm + lq*256 + h*32;
      const float* bk = b_in + 256 + h*32;
      float s=0.f;
      #pragma unroll
      for (int d=0;d<32;d++) s += qp[d]*bk[d];
      U[j] = s*inv;
    } else if (id < 33792){
      int j = id - 33280; int h = j>>6, lk = j&63;
      const float* kp = Km + lk*256 + h*32;
      const float* bq = b_in + h*32;
      float s=0.f;
      #pragma unroll
      for (int d=0;d<32;d++) s += bq[d]*kp[d];
      W[j] = s*inv;
    } else if (id < 33800){
      int h = id - 33792;
      float s=0.f;
      #pragma unroll
      for (int d=0;d<32;d++) s += b_in[h*32+d]*b_in[256+h*32+d];
      S[h] = s*inv;
    } else if (id < 34056){
      int e = id - 33800;
      float s = b_ao[e];
      for (int d=0; d<256; d++) s += b_in[512+d]*W_ao[e*256+d];
      abias[e] = s;
    }
    return;
  }
  if (bid < 646){
    int id = (bid-134)*256 + tid;   // 131072 = 256*512
    int e = id >> 9, kk = id & 511;
    int h = kk >> 6, lk = kk & 63;
    const float* vp = Vm + lk*256 + h*32;
    const float* wp = W_ao + e*256 + h*32;
    float s=0.f;
    #pragma unroll
    for (int d=0;d<32;d++) s += vp[d]*wp[d];
    M2t[id] = (short)f2b(s);
    return;
  }
  if (bid < 2694){
    int id = (bid-646)*256 + tid;   // 524288
    if (id < 262144) W1b[id] = (short)f2b(W1[id]);
    else             W2b[id-262144] = (short)f2b(W2[id-262144]);
    return;
  }
  // ---- RNN: blocks 2694..2709, lanes 0..63 active ----
  {
    int b = bid - 2694;
    int l = tid;
    bool act = (l < 64);
    __shared__ float h_sh[64];
    __shared__ float fh_sh[24];
    __shared__ float WfpT[24][64];
    float wr[64];
    float wih=0, bb=0, bf=0;
    float uf0=0,uf1=0,uf2=0,uf3=0;
    if (act){
      #pragma unroll
      for (int j=0;j<64;j++) wr[j] = W_hh[l*64+j];
      #pragma unroll
      for (int j=0;j<24;j++) WfpT[j][l] = Wfp[l*24+j];
      wih = W_ih[l];
      bb  = b_ih[l] + b_hh[l];
      bf  = bfp[l];
      if (l < 24){ uf0=Uf[l*4+0]; uf1=Uf[l*4+1]; uf2=Uf[l*4+2]; uf3=Uf[l*4+3]; }
      h_sh[l] = z0[l];
    }
    __syncthreads();
    const float* xb = x_cont + (size_t)b*128*97;
    for (int t=0;t<128;t++){
      float hn = 0.f, fh = 0.f;
      if (act){
        float x0 = xb[t*97];
        float a0=0,a1=0,a2=0,a3=0;
        #pragma unroll
        for (int j=0;j<64;j+=4){
          a0 += wr[j  ]*h_sh[j  ];
          a1 += wr[j+1]*h_sh[j+1];
          a2 += wr[j+2]*h_sh[j+2];
          a3 += wr[j+3]*h_sh[j+3];
        }
        hn = fmaxf(x0*wih + bb + ((a0+a1)+(a2+a3)), 0.f);
        if (l < 24){
          const float* xf = xb + t*97 + 1 + l*4;
          fh = xf[0]*uf0 + xf[1]*uf1 + xf[2]*uf2 + xf[3]*uf3;
        }
      }
      __syncthreads();
      if (act){
        h_sh[l] = hn;
        if (l < 24) fh_sh[l] = fh;
      }
      __syncthreads();
      if (act){
        float zv = hn + bf;
        #pragma unroll
        for (int j=0;j<24;j++) zv += fh_sh[j]*WfpT[j][l];
        zout[((size_t)b*128 + t)*64 + l] = zv;
      }
    }
  }
}

// ---------------- fused per-token transformer block (2048 blocks x 256 thr) ----------------
// Transposed-acc: acc[et][tt] elem r -> (e = cb+et*16+lg*4+r, tok = tt*16+lr).
// Attention softmax computed directly in B-frag layout: lane (lr,lg) owns
// P(lq=tt*16+lr, lk=ks*32+lg*8+j) -> zero barriers, no attz LDS.
__global__ __launch_bounds__(256, 3) void k_main(
  const float* __restrict__ zall, const float* __restrict__ Gmat,
  const float* __restrict__ Ubuf, const float* __restrict__ Wbuf, const float* __restrict__ Sbuf,
  const float* __restrict__ abias, const short* __restrict__ M2t,
  const float* __restrict__ FE,
  const short* __restrict__ W1b, const float* __restrict__ b1,
  const short* __restrict__ W2b, const float* __restrict__ b2,
  const float* __restrict__ g1, const float* __restrict__ be1,
  const float* __restrict__ g2, const float* __restrict__ be2,
  const float* __restrict__ Wop, const float* __restrict__ bop,
  const float* __restrict__ Wg, const float* __restrict__ bg,
  const float* __restrict__ Amat, const float* __restrict__ cvec,
  float* __restrict__ out)
{
  const int n = blockIdx.x;
  const int tid = threadIdx.x;
  const int w = tid >> 6, lane = tid & 63, lg = lane >> 4, lr = lane & 15;
  const int cb = w * 64;

  __shared__ __align__(16) short t1_sh[64][262];   // 33536 B (stride 524B = 131 banks, odd mod 32)
  __shared__ __align__(16) short mid_sh[64][134];  // 17152 B (stride 268B = 67 banks, odd mod 32)
  __shared__ float redA[4][64];                    // 1024
  __shared__ float redB[4][64];                    // 1024
  __shared__ float z_sh[64];                       // 256   -> total 52992 B -> 3 blocks/CU

  if (tid < 64) z_sh[tid] = zall[n*64 + tid];
  __syncthreads();   // Z0

  // per-lane z slices for attention
  float zkf[16];     // z[lk], lk = (i>>3)*32 + lg*8 + (i&7)
  #pragma unroll
  for (int i=0;i<16;i++) zkf[i] = z_sh[(i>>3)*32 + lg*8 + (i&7)];
  float zqv[4];
  #pragma unroll
  for (int tt=0;tt<4;tt++) zqv[tt] = z_sh[tt*16 + lr];

  // ---------- attention (in-register softmax, 0 barriers) ----------
  f32x4 acc[4][4];
  #pragma unroll
  for (int et=0;et<4;et++)
    #pragma unroll
    for (int tt=0;tt<4;tt++){ f32x4 zz = {0.f,0.f,0.f,0.f}; acc[et][tt] = zz; }

  #pragma unroll 1
  for (int h=0; h<8; ++h){
    const float sh = Sbuf[h];
    float wpf[16];
    #pragma unroll
    for (int ks=0;ks<2;ks++){
      f32x4 wa = *(const f32x4*)(Wbuf + h*64 + ks*32 + lg*8);
      f32x4 wb = *(const f32x4*)(Wbuf + h*64 + ks*32 + lg*8 + 4);
      #pragma unroll
      for (int j=0;j<4;j++){ wpf[ks*8+j] = wa[j]; wpf[ks*8+4+j] = wb[j]; }
    }
    bf16x8 am[2][4];
    #pragma unroll
    for (int ks=0;ks<2;ks++)
      #pragma unroll
      for (int et=0;et<4;et++)
        am[ks][et] = *(const bf16x8*)(M2t + (size_t)(cb+et*16+lr)*512 + h*64 + ks*32 + lg*8);

    #pragma unroll
    for (int tt=0;tt<4;tt++){
      const int lq = tt*16 + lr;
      const float uh = Ubuf[h*64 + lq];
      const float zq = zqv[tt];
      float e0[16];
      #pragma unroll
      for (int ks=0;ks<2;ks++){
        f32x4 ga = *(const f32x4*)(Gmat + (size_t)(h*64+lq)*64 + ks*32 + lg*8);
        f32x4 gb = *(const f32x4*)(Gmat + (size_t)(h*64+lq)*64 + ks*32 + lg*8 + 4);
        #pragma unroll
        for (int j=0;j<4;j++){
          float zk = zkf[ks*8+j];
          e0[ks*8+j] = zq*(zk*ga[j] + uh) + (zk*wpf[ks*8+j] + sh);
          float zk2 = zkf[ks*8+4+j];
          e0[ks*8+4+j] = zq*(zk2*gb[j] + uh) + (zk2*wpf[ks*8+4+j] + sh);
        }
      }
      float mx = e0[0];
      #pragma unroll
      for (int i=1;i<16;i++) mx = fmaxf(mx, e0[i]);
      mx = fmaxf(mx, __shfl_xor(mx,16));
      mx = fmaxf(mx, __shfl_xor(mx,32));
      float sum = 0.f;
      #pragma unroll
      for (int i=0;i<16;i++){ e0[i] = __expf(e0[i]-mx); sum += e0[i]; }
      sum += __shfl_xor(sum,16);
      sum += __shfl_xor(sum,32);
      float inv = 1.f/sum;
      union { bf16x8 v; unsigned u[4]; } pa[2];
      #pragma unroll
      for (int ks=0;ks<2;ks++)
        #pragma unroll
        for (int p=0;p<4;p++)
          pa[ks].u[p] = pk2(e0[ks*8+2*p]*inv*zkf[ks*8+2*p], e0[ks*8+2*p+1]*inv*zkf[ks*8+2*p+1]);
      #pragma unroll
      for (int ks=0;ks<2;ks++)
        #pragma unroll
        for (int et=0;et<4;et++)
          acc[et][tt] = __builtin_amdgcn_mfma_f32_16x16x32_bf16(am[ks][et], pa[ks].v, acc[et][tt], 0,0,0);
    }
  }

  // ---------- t1 = LN(tokens + aop) ----------
  f32x4 ab4[4], g14[4], be14[4];
  #pragma unroll
  for (int et=0;et<4;et++){
    int e0_ = cb + et*16 + lg*4;
    ab4[et]  = *(const f32x4*)(abias + e0_);
    g14[et]  = *(const f32x4*)(g1 + e0_);
    be14[et] = *(const f32x4*)(be1 + e0_);
  }
  float sum1[4], ssq1[4];
  #pragma unroll
  for (int tt=0;tt<4;tt++){
    int tok = tt*16 + lr;
    float zt = z_sh[tok];
    float s = 0.f, sq = 0.f;
    #pragma unroll
    for (int et=0;et<4;et++){
      f32x4 fe = *(const f32x4*)(FE + (size_t)tok*256 + cb + et*16 + lg*4);
      #pragma unroll
      for (int r=0;r<4;r++){
        float v = acc[et][tt][r] + ab4[et][r] + zt*fe[r];
        acc[et][tt][r] = v; s += v; sq += v*v;
      }
    }
    s  += __shfl_xor(s,16);  s  += __shfl_xor(s,32);
    sq += __shfl_xor(sq,16); sq += __shfl_xor(sq,32);
    sum1[tt] = s; ssq1[tt] = sq;
  }
  if (lane < 16){
    #pragma unroll
    for (int tt=0;tt<4;tt++){ redA[w][tt*16+lane] = sum1[tt]; redB[w][tt*16+lane] = ssq1[tt]; }
  }
  __syncthreads();   // S1
  float mu1[4], rs1[4];
  #pragma unroll
  for (int tt=0;tt<4;tt++){
    int tok = tt*16 + lr;
    float s  = redA[0][tok] + redA[1][tok] + redA[2][tok] + redA[3][tok];
    float sq = redB[0][tok] + redB[1][tok] + redB[2][tok] + redB[3][tok];
    float m = s * (1.f/256.f);
    mu1[tt] = m;
    rs1[tt] = rsqrtf(sq*(1.f/256.f) - m*m + 1e-5f);
  }
  #pragma unroll
  for (int et=0;et<4;et++)
    #pragma unroll
    for (int tt=0;tt<4;tt++){
      uint2 p;
      float v0 = (acc[et][tt][0]-mu1[tt])*rs1[tt]*g14[et][0] + be14[et][0];
      float v1 = (acc[et][tt][1]-mu1[tt])*rs1[tt]*g14[et][1] + be14[et][1];
      float v2 = (acc[et][tt][2]-mu1[tt])*rs1[tt]*g14[et][2] + be14[et][2];
      float v3 = (acc[et][tt][3]-mu1[tt])*rs1[tt]*g14[et][3] + be14[et][3];
      p.x = pk2(v0,v1); p.y = pk2(v2,v3);
      *(uint2*)&t1_sh[tt*16+lr][cb + et*16 + lg*4] = p;
    }
  __syncthreads();   // T1: t1 ready

  // ---------- FFN: 8 chunks of 128 mid-channels ----------
  f32x4 outv[4][4];
  #pragma unroll
  for (int et=0;et<4;et++)
    #pragma unroll
    for (int tt=0;tt<4;tt++){ f32x4 zz = {0.f,0.f,0.f,0.f}; outv[et][tt] = zz; }

  #pragma unroll 1
  for (int c=0; c<8; c++){
    f32x4 midv[2][4];
    #pragma unroll
    for (int ct=0;ct<2;ct++){
      f32x4 bi = *(const f32x4*)(b1 + c*128 + w*32 + ct*16 + lg*4);
      #pragma unroll
      for (int tt=0;tt<4;tt++) midv[ct][tt] = bi;
    }
    #pragma unroll
    for (int ks=0; ks<8; ks++){
      bf16x8 bt[4], aw[2];
      #pragma unroll
      for (int tt=0;tt<4;tt++) bt[tt] = *(const bf16x8*)&t1_sh[tt*16+lr][ks*32 + lg*8];
      #pragma unroll
      for (int ct=0;ct<2;ct++)
        aw[ct] = *(const bf16x8*)(W1b + (size_t)(c*128 + w*32 + ct*16 + lr)*256 + ks*32 + lg*8);
      #pragma unroll
      for (int ct=0;ct<2;ct++)
        #pragma unroll
        for (int tt=0;tt<4;tt++)
          midv[ct][tt] = __builtin_amdgcn_mfma_f32_16x16x32_bf16(aw[ct], bt[tt], midv[ct][tt], 0,0,0);
    }
    __syncthreads();       // prior FFN2 reads of mid done
    #pragma unroll
    for (int ct=0;ct<2;ct++)
      #pragma unroll
      for (int tt=0;tt<4;tt++){
        uint2 p;
        p.x = pk2(fmaxf(midv[ct][tt][0],0.f), fmaxf(midv[ct][tt][1],0.f));
        p.y = pk2(fmaxf(midv[ct][tt][2],0.f), fmaxf(midv[ct][tt][3],0.f));
        *(uint2*)&mid_sh[tt*16+lr][w*32 + ct*16 + lg*4] = p;
      }
    __syncthreads();
    #pragma unroll
    for (int ks=0; ks<4; ks++){
      bf16x8 bm[4], aw2[4];
      #pragma unroll
      for (int tt=0;tt<4;tt++) bm[tt] = *(const bf16x8*)&mid_sh[tt*16+lr][ks*32 + lg*8];
      #pragma unroll
      for (int et=0;et<4;et++)
        aw2[et] = *(const bf16x8*)(W2b + (size_t)(cb+et*16+lr)*1024 + c*128 + ks*32 + lg*8);
      #pragma unroll
      for (int et=0;et<4;et++)
        #pragma unroll
        for (int tt=0;tt<4;tt++)
          outv[et][tt] = __builtin_amdgcn_mfma_f32_16x16x32_bf16(aw2[et], bm[tt], outv[et][tt], 0,0,0);
    }
  }

  // ---------- t2 = LN(t1 + ffn), delta, z_out, o ----------
  f32x4 b24[4];
  #pragma unroll
  for (int et=0;et<4;et++) b24[et] = *(const f32x4*)(b2 + cb + et*16 + lg*4);
  float sum2[4], ssq2[4];
  #pragma unroll
  for (int tt=0;tt<4;tt++){
    int tok = tt*16 + lr;
    float s = 0.f, sq = 0.f;
    #pragma unroll
    for (int et=0;et<4;et++){
      uint2 t1v = *(const uint2*)&t1_sh[tok][cb + et*16 + lg*4];
      #pragma unroll
      for (int r=0;r<4;r++){
        unsigned short hs = (unsigned short)((r&1) ? ((r<2?t1v.x:t1v.y)>>16) : ((r<2?t1v.x:t1v.y)&0xFFFF));
        float v = outv[et][tt][r] + b24[et][r] + b2f(hs);
        outv[et][tt][r] = v; s += v; sq += v*v;
      }
    }
    s  += __shfl_xor(s,16);  s  += __shfl_xor(s,32);
    sq += __shfl_xor(sq,16); sq += __shfl_xor(sq,32);
    sum2[tt] = s; ssq2[tt] = sq;
  }
  if (lane < 16){
    #pragma unroll
    for (int tt=0;tt<4;tt++){ redA[w][tt*16+lane] = sum2[tt]; redB[w][tt*16+lane] = ssq2[tt]; }
  }
  __syncthreads();   // B2

  float gate = 0.f;
  if (tid < 64){
    float gacc = bg[tid];
    const f32x4* wgr = (const f32x4*)(Wg + tid*64);
    #pragma unroll
    for (int j=0;j<16;j++){
      f32x4 wv = wgr[j];
      f32x4 zv = *(const f32x4*)(z_sh + j*4);
      gacc += wv[0]*zv[0] + wv[1]*zv[1] + wv[2]*zv[2] + wv[3]*zv[3];
    }
    gate = 1.f/(1.f + __expf(-gacc));
  }

  f32x4 g24[4], be24[4], wop4[4];
  #pragma unroll
  for (int et=0;et<4;et++){
    int e0_ = cb + et*16 + lg*4;
    g24[et]  = *(const f32x4*)(g2 + e0_);
    be24[et] = *(const f32x4*)(be2 + e0_);
    wop4[et] = *(const f32x4*)(Wop + e0_);
  }
  float dpart[4];
  #pragma unroll
  for (int tt=0;tt<4;tt++){
    int tok = tt*16 + lr;
    float s  = redA[0][tok] + redA[1][tok] + redA[2][tok] + redA[3][tok];
    float sq = redB[0][tok] + redB[1][tok] + redB[2][tok] + redB[3][tok];
    float m = s * (1.f/256.f);
    float rs = rsqrtf(sq*(1.f/256.f) - m*m + 1e-5f);
    float d = 0.f;
    #pragma unroll
    for (int et=0;et<4;et++)
      #pragma unroll
      for (int r=0;r<4;r++){
        float t2 = (outv[et][tt][r]-m)*rs*g24[et][r] + be24[et][r];
        d += t2*wop4[et][r];
      }
    d += __shfl_xor(d,16); d += __shfl_xor(d,32);
    dpart[tt] = d;
  }
  __syncthreads();   // N1: protect redA rewrite
  if (lane < 16){
    #pragma unroll
    for (int tt=0;tt<4;tt++) redA[w][tt*16+lane] = dpart[tt];
  }
  __syncthreads();   // D2
  if (tid < 64){
    float delta = redA[0][tid]+redA[1][tid]+redA[2][tid]+redA[3][tid] + bop[0];
    float zo = z_sh[tid] + gate*delta;
    out[49152 + (size_t)n*64 + tid] = zo;
    z_sh[tid] = zo;
  }
  __syncthreads();   // E2
  if (tid < 24){
    const float* ar = Amat + tid*64;
    float s = cvec[tid];
    #pragma unroll
    for (int j=0;j<64;j++) s += z_sh[j]*ar[j];
    out[(size_t)n*24 + tid] = s;
  }
}

extern "C" void kernel_launch(void* const* d_in, const int* in_sizes, int n_in,
                              void* d_out, int out_size, void* d_ws, size_t ws_size,
                              hipStream_t stream) {
  const float* x_cont = (const float*)d_in[0];
  const float* z0    = (const float*)d_in[1];
  const float* W_ih  = (const float*)d_in[2];
  const float* W_hh  = (const float*)d_in[3];
  const float* b_ih  = (const float*)d_in[4];
  const float* b_hh  = (const float*)d_in[5];
  const float* Uf    = (const float*)d_in[6];
  const float* Wfp   = (const float*)d_in[7];
  const float* bfp   = (const float*)d_in[8];
  const float* FE    = (const float*)d_in[9];
  const float* W_in  = (const float*)d_in[10];
  const float* b_in  = (const float*)d_in[11];
  const float* W_ao  = (const float*)d_in[12];
  const float* b_ao  = (const float*)d_in[13];
  const float* g1    = (const float*)d_in[14];
  const float* be1   = (const float*)d_in[15];
  const float* W1    = (const float*)d_in[16];
  const float* b1    = (const float*)d_in[17];
  const float* W2    = (const float*)d_in[18];
  const float* b2    = (const float*)d_in[19];
  const float* g2    = (const float*)d_in[20];
  const float* be2   = (const float*)d_in[21];
  const float* Wop   = (const float*)d_in[22];
  const float* bop   = (const float*)d_in[23];
  const float* Wg    = (const float*)d_in[24];
  const float* bg    = (const float*)d_in[25];
  const float* Amat  = (const float*)d_in[26];
  const float* cvec  = (const float*)d_in[27];
  float* out = (float*)d_out;
  char* ws = (char*)d_ws;

  float* z    = (float*)(ws + 0);         // 2048*64*4
  float* Qm   = (float*)(ws + 524288);
  float* Km   = (float*)(ws + 589824);
  float* Vm   = (float*)(ws + 655360);
  float* G    = (float*)(ws + 720896);    // 8*64*64*4
  float* U    = (float*)(ws + 851968);
  float* Wb   = (float*)(ws + 854016);
  float* S    = (float*)(ws + 856064);
  float* ab   = (float*)(ws + 856320);
  short* M2t  = (short*)(ws + 857344);    // 256*512*2
  short* W1b  = (short*)(ws + 1119488);   // 1024*256*2
  short* W2b  = (short*)(ws + 1643776);   // 256*1024*2

  hipLaunchKernelGGL(k_pre_qkv, dim3(192), dim3(256), 0, stream, FE, W_in, Qm, Km, Vm);
  hipLaunchKernelGGL(k_pre2, dim3(2710), dim3(256), 0, stream,
                     Qm, Km, Vm, b_in, W_ao, b_ao, G, U, Wb, S, ab, M2t,
                     W1, W2, W1b, W2b,
                     x_cont, z0, W_ih, W_hh, b_ih, b_hh, Uf, Wfp, bfp, z);
  hipLaunchKernelGGL(k_main, dim3(2048), dim3(256), 0, stream, z, G, U, Wb, S, ab, M2t, FE,
                     W1b, b1, W2b, b2, g1, be1, g2, be2, Wop, bop, Wg, bg, Amat, cvec, out);
}

// Round 4
// 595.119 us; speedup vs baseline: 1.3250x; 1.3250x over previous
//
#include <hip/hip_runtime.h>

typedef short bf16x8 __attribute__((ext_vector_type(8)));
typedef float f32x4  __attribute__((ext_vector_type(4)));

__device__ __forceinline__ unsigned short f2b(float f){
  union { float f; unsigned u; } v; v.f = f;
  unsigned r = v.u + 0x7FFFu + ((v.u >> 16) & 1u);
  return (unsigned short)(r >> 16);
}
__device__ __forceinline__ float b2f(unsigned short s){
  union { unsigned u; float f; } v; v.u = ((unsigned)s) << 16;
  return v.f;
}
// pack two f32 -> one u32 of 2x bf16 (RNE) in one VALU op
__device__ __forceinline__ unsigned pk2(float lo, float hi){
  unsigned r;
  asm("v_cvt_pk_bf16_f32 %0, %1, %2" : "=v"(r) : "v"(lo), "v"(hi));
  return r;
}

// ---------------- stage 1: Qm/Km/Vm = FE @ W_in^T  (3 x 64 x 256) ----------------
__global__ void k_pre_qkv(const float* __restrict__ FE, const float* __restrict__ W_in,
                          float* __restrict__ Qm, float* __restrict__ Km, float* __restrict__ Vm){
  int id = blockIdx.x*256 + threadIdx.x;      // 49152
  int part = id >> 14;
  int l = (id >> 8) & 63;
  int d = id & 255;
  const float4* fe = (const float4*)(FE + l*256);
  const float4* wr = (const float4*)(W_in + (part*256 + d)*256);
  float s = 0.f;
  #pragma unroll 8
  for (int k=0;k<64;k++){
    float4 a = fe[k], b = wr[k];
    s += a.x*b.x + a.y*b.y + a.z*b.z + a.w*b.w;
  }
  float* dst = (part==0)?Qm:((part==1)?Km:Vm);
  dst[l*256+d] = s;
}

// ---------------- stage 2 (merged): att-tables + M2t + weight cvt + RNN ----------------
__global__ void k_pre2(const float* __restrict__ Qm, const float* __restrict__ Km,
                       const float* __restrict__ Vm,
                       const float* __restrict__ b_in, const float* __restrict__ W_ao,
                       const float* __restrict__ b_ao,
                       float* __restrict__ G, float* __restrict__ U,
                       float* __restrict__ W, float* __restrict__ S,
                       float* __restrict__ abias, short* __restrict__ M2t,
                       const float* __restrict__ W1, const float* __restrict__ W2,
                       short* __restrict__ W1b, short* __restrict__ W2b,
                       const float* __restrict__ x_cont, const float* __restrict__ z0,
                       const float* __restrict__ W_ih, const float* __restrict__ W_hh,
                       const float* __restrict__ b_ih, const float* __restrict__ b_hh,
                       const float* __restrict__ Uf, const float* __restrict__ Wfp,
                       const float* __restrict__ bfp, float* __restrict__ zout){
  int bid = blockIdx.x;
  int tid = threadIdx.x;
  if (bid < 134){
    int id = bid*256 + tid;
    const float inv = 0.17677669529663687f;   // 1/sqrt(32)
    if (id < 32768){
      int h = id >> 12, lq = (id>>6)&63, lk = id&63;
      const float* qp = Qm + lq*256 + h*32;
      const float* kp = Km + lk*256 + h*32;
      float s=0.f;
      #pragma unroll
      for (int d=0;d<32;d++) s += qp[d]*kp[d];
      G[id] = s*inv;
    } else if (id < 33280){
      int j = id - 32768; int h = j>>6, lq = j&63;
      const float* qp = Qm + lq*256 + h*32;
      const float* bk = b_in + 256 + h*32;
      float s=0.f;
      #pragma unroll
      for (int d=0;d<32;d++) s += qp[d]*bk[d];
      U[j] = s*inv;
    } else if (id < 33792){
      int j = id - 33280; int h = j>>6, lk = j&63;
      const float* kp = Km + lk*256 + h*32;
      const float* bq = b_in + h*32;
      float s=0.f;
      #pragma unroll
      for (int d=0;d<32;d++) s += bq[d]*kp[d];
      W[j] = s*inv;
    } else if (id < 33800){
      int h = id - 33792;
      float s=0.f;
      #pragma unroll
      for (int d=0;d<32;d++) s += b_in[h*32+d]*b_in[256+h*32+d];
      S[h] = s*inv;
    } else if (id < 34056){
      int e = id - 33800;
      float s = b_ao[e];
      for (int d=0; d<256; d++) s += b_in[512+d]*W_ao[e*256+d];
      abias[e] = s;
    }
    return;
  }
  if (bid < 646){
    int id = (bid-134)*256 + tid;   // 131072 = 256*512
    int e = id >> 9, kk = id & 511;
    int h = kk >> 6, lk = kk & 63;
    const float* vp = Vm + lk*256 + h*32;
    const float* wp = W_ao + e*256 + h*32;
    float s=0.f;
    #pragma unroll
    for (int d=0;d<32;d++) s += vp[d]*wp[d];
    M2t[id] = (short)f2b(s);
    return;
  }
  if (bid < 2694){
    int id = (bid-646)*256 + tid;   // 524288
    if (id < 262144) W1b[id] = (short)f2b(W1[id]);
    else             W2b[id-262144] = (short)f2b(W2[id-262144]);
    return;
  }
  // ---- RNN: blocks 2694..2709, lanes 0..63 active ----
  {
    int b = bid - 2694;
    int l = tid;
    bool act = (l < 64);
    __shared__ float h_sh[64];
    __shared__ float fh_sh[24];
    __shared__ float WfpT[24][64];
    float wr[64];
    float wih=0, bb=0, bf=0;
    float uf0=0,uf1=0,uf2=0,uf3=0;
    if (act){
      #pragma unroll
      for (int j=0;j<64;j++) wr[j] = W_hh[l*64+j];
      #pragma unroll
      for (int j=0;j<24;j++) WfpT[j][l] = Wfp[l*24+j];
      wih = W_ih[l];
      bb  = b_ih[l] + b_hh[l];
      bf  = bfp[l];
      if (l < 24){ uf0=Uf[l*4+0]; uf1=Uf[l*4+1]; uf2=Uf[l*4+2]; uf3=Uf[l*4+3]; }
      h_sh[l] = z0[l];
    }
    __syncthreads();
    const float* xb = x_cont + (size_t)b*128*97;
    for (int t=0;t<128;t++){
      float hn = 0.f, fh = 0.f;
      if (act){
        float x0 = xb[t*97];
        float a0=0,a1=0,a2=0,a3=0;
        #pragma unroll
        for (int j=0;j<64;j+=4){
          a0 += wr[j  ]*h_sh[j  ];
          a1 += wr[j+1]*h_sh[j+1];
          a2 += wr[j+2]*h_sh[j+2];
          a3 += wr[j+3]*h_sh[j+3];
        }
        hn = fmaxf(x0*wih + bb + ((a0+a1)+(a2+a3)), 0.f);
        if (l < 24){
          const float* xf = xb + t*97 + 1 + l*4;
          fh = xf[0]*uf0 + xf[1]*uf1 + xf[2]*uf2 + xf[3]*uf3;
        }
      }
      __syncthreads();
      if (act){
        h_sh[l] = hn;
        if (l < 24) fh_sh[l] = fh;
      }
      __syncthreads();
      if (act){
        float zv = hn + bf;
        #pragma unroll
        for (int j=0;j<24;j++) zv += fh_sh[j]*WfpT[j][l];
        zout[((size_t)b*128 + t)*64 + l] = zv;
      }
    }
  }
}

// ---------------- fused per-token transformer block (2048 blocks x 256 thr) ----------------
// Transposed-acc: acc[et][tt] elem r -> (e = cb+et*16+lg*4+r, tok = tt*16+lr).
// Attention softmax computed directly in B-frag layout: lane (lr,lg) owns
// P(lq=tt*16+lr, lk=ks*32+lg*8+j) -> zero barriers, no attz LDS.
// launch_bounds (256,2): 256-VGPR budget -- (256,3) caused full array spill (R3).
__global__ __launch_bounds__(256, 2) void k_main(
  const float* __restrict__ zall, const float* __restrict__ Gmat,
  const float* __restrict__ Ubuf, const float* __restrict__ Wbuf, const float* __restrict__ Sbuf,
  const float* __restrict__ abias, const short* __restrict__ M2t,
  const float* __restrict__ FE,
  const short* __restrict__ W1b, const float* __restrict__ b1,
  const short* __restrict__ W2b, const float* __restrict__ b2,
  const float* __restrict__ g1, const float* __restrict__ be1,
  const float* __restrict__ g2, const float* __restrict__ be2,
  const float* __restrict__ Wop, const float* __restrict__ bop,
  const float* __restrict__ Wg, const float* __restrict__ bg,
  const float* __restrict__ Amat, const float* __restrict__ cvec,
  float* __restrict__ out)
{
  const int n = blockIdx.x;
  const int tid = threadIdx.x;
  const int w = tid >> 6, lane = tid & 63, lg = lane >> 4, lr = lane & 15;
  const int cb = w * 64;

  __shared__ __align__(16) short t1_sh[64][262];   // 33536 B
  __shared__ __align__(16) short mid_sh[64][134];  // 17152 B
  __shared__ float redA[4][64];                    // 1024
  __shared__ float redB[4][64];                    // 1024
  __shared__ float z_sh[64];                       // 256

  if (tid < 64) z_sh[tid] = zall[n*64 + tid];
  __syncthreads();   // Z0

  // per-lane z slices for attention
  float zkf[16];     // z[lk], lk = (i>>3)*32 + lg*8 + (i&7)
  #pragma unroll
  for (int i=0;i<16;i++) zkf[i] = z_sh[(i>>3)*32 + lg*8 + (i&7)];
  float zqv[4];
  #pragma unroll
  for (int tt=0;tt<4;tt++) zqv[tt] = z_sh[tt*16 + lr];

  // ---------- attention (in-register softmax, 0 barriers) ----------
  f32x4 acc[4][4];
  #pragma unroll
  for (int et=0;et<4;et++)
    #pragma unroll
    for (int tt=0;tt<4;tt++){ f32x4 zz = {0.f,0.f,0.f,0.f}; acc[et][tt] = zz; }

  #pragma unroll 1
  for (int h=0; h<8; ++h){
    const float sh = Sbuf[h];
    float wpf[16];
    #pragma unroll
    for (int ks=0;ks<2;ks++){
      f32x4 wa = *(const f32x4*)(Wbuf + h*64 + ks*32 + lg*8);
      f32x4 wb = *(const f32x4*)(Wbuf + h*64 + ks*32 + lg*8 + 4);
      #pragma unroll
      for (int j=0;j<4;j++){ wpf[ks*8+j] = wa[j]; wpf[ks*8+4+j] = wb[j]; }
    }
    bf16x8 am[2][4];
    #pragma unroll
    for (int ks=0;ks<2;ks++)
      #pragma unroll
      for (int et=0;et<4;et++)
        am[ks][et] = *(const bf16x8*)(M2t + (size_t)(cb+et*16+lr)*512 + h*64 + ks*32 + lg*8);

    #pragma unroll
    for (int tt=0;tt<4;tt++){
      const int lq = tt*16 + lr;
      const float uh = Ubuf[h*64 + lq];
      const float zq = zqv[tt];
      float e0[16];
      #pragma unroll
      for (int ks=0;ks<2;ks++){
        f32x4 ga = *(const f32x4*)(Gmat + (size_t)(h*64+lq)*64 + ks*32 + lg*8);
        f32x4 gb = *(const f32x4*)(Gmat + (size_t)(h*64+lq)*64 + ks*32 + lg*8 + 4);
        #pragma unroll
        for (int j=0;j<4;j++){
          float zk = zkf[ks*8+j];
          e0[ks*8+j] = zq*(zk*ga[j] + uh) + (zk*wpf[ks*8+j] + sh);
          float zk2 = zkf[ks*8+4+j];
          e0[ks*8+4+j] = zq*(zk2*gb[j] + uh) + (zk2*wpf[ks*8+4+j] + sh);
        }
      }
      float mx = e0[0];
      #pragma unroll
      for (int i=1;i<16;i++) mx = fmaxf(mx, e0[i]);
      mx = fmaxf(mx, __shfl_xor(mx,16));
      mx = fmaxf(mx, __shfl_xor(mx,32));
      float sum = 0.f;
      #pragma unroll
      for (int i=0;i<16;i++){ e0[i] = __expf(e0[i]-mx); sum += e0[i]; }
      sum += __shfl_xor(sum,16);
      sum += __shfl_xor(sum,32);
      float inv = 1.f/sum;
      union { bf16x8 v; unsigned u[4]; } pa[2];
      #pragma unroll
      for (int ks=0;ks<2;ks++)
        #pragma unroll
        for (int p=0;p<4;p++)
          pa[ks].u[p] = pk2(e0[ks*8+2*p]*inv*zkf[ks*8+2*p], e0[ks*8+2*p+1]*inv*zkf[ks*8+2*p+1]);
      #pragma unroll
      for (int ks=0;ks<2;ks++)
        #pragma unroll
        for (int et=0;et<4;et++)
          acc[et][tt] = __builtin_amdgcn_mfma_f32_16x16x32_bf16(am[ks][et], pa[ks].v, acc[et][tt], 0,0,0);
    }
  }

  // ---------- t1 = LN(tokens + aop) ----------
  f32x4 ab4[4], g14[4], be14[4];
  #pragma unroll
  for (int et=0;et<4;et++){
    int e0_ = cb + et*16 + lg*4;
    ab4[et]  = *(const f32x4*)(abias + e0_);
    g14[et]  = *(const f32x4*)(g1 + e0_);
    be14[et] = *(const f32x4*)(be1 + e0_);
  }
  float sum1[4], ssq1[4];
  #pragma unroll
  for (int tt=0;tt<4;tt++){
    int tok = tt*16 + lr;
    float zt = z_sh[tok];
    float s = 0.f, sq = 0.f;
    #pragma unroll
    for (int et=0;et<4;et++){
      f32x4 fe = *(const f32x4*)(FE + (size_t)tok*256 + cb + et*16 + lg*4);
      #pragma unroll
      for (int r=0;r<4;r++){
        float v = acc[et][tt][r] + ab4[et][r] + zt*fe[r];
        acc[et][tt][r] = v; s += v; sq += v*v;
      }
    }
    s  += __shfl_xor(s,16);  s  += __shfl_xor(s,32);
    sq += __shfl_xor(sq,16); sq += __shfl_xor(sq,32);
    sum1[tt] = s; ssq1[tt] = sq;
  }
  if (lane < 16){
    #pragma unroll
    for (int tt=0;tt<4;tt++){ redA[w][tt*16+lane] = sum1[tt]; redB[w][tt*16+lane] = ssq1[tt]; }
  }
  __syncthreads();   // S1
  float mu1[4], rs1[4];
  #pragma unroll
  for (int tt=0;tt<4;tt++){
    int tok = tt*16 + lr;
    float s  = redA[0][tok] + redA[1][tok] + redA[2][tok] + redA[3][tok];
    float sq = redB[0][tok] + redB[1][tok] + redB[2][tok] + redB[3][tok];
    float m = s * (1.f/256.f);
    mu1[tt] = m;
    rs1[tt] = rsqrtf(sq*(1.f/256.f) - m*m + 1e-5f);
  }
  #pragma unroll
  for (int et=0;et<4;et++)
    #pragma unroll
    for (int tt=0;tt<4;tt++){
      uint2 p;
      float v0 = (acc[et][tt][0]-mu1[tt])*rs1[tt]*g14[et][0] + be14[et][0];
      float v1 = (acc[et][tt][1]-mu1[tt])*rs1[tt]*g14[et][1] + be14[et][1];
      float v2 = (acc[et][tt][2]-mu1[tt])*rs1[tt]*g14[et][2] + be14[et][2];
      float v3 = (acc[et][tt][3]-mu1[tt])*rs1[tt]*g14[et][3] + be14[et][3];
      p.x = pk2(v0,v1); p.y = pk2(v2,v3);
      *(uint2*)&t1_sh[tt*16+lr][cb + et*16 + lg*4] = p;
    }
  __syncthreads();   // T1: t1 ready

  // ---------- FFN: 8 chunks of 128 mid-channels ----------
  f32x4 outv[4][4];
  #pragma unroll
  for (int et=0;et<4;et++)
    #pragma unroll
    for (int tt=0;tt<4;tt++){ f32x4 zz = {0.f,0.f,0.f,0.f}; outv[et][tt] = zz; }

  #pragma unroll 1
  for (int c=0; c<8; c++){
    f32x4 midv[2][4];
    #pragma unroll
    for (int ct=0;ct<2;ct++){
      f32x4 bi = *(const f32x4*)(b1 + c*128 + w*32 + ct*16 + lg*4);
      #pragma unroll
      for (int tt=0;tt<4;tt++) midv[ct][tt] = bi;
    }
    #pragma unroll
    for (int ks=0; ks<8; ks++){
      bf16x8 bt[4], aw[2];
      #pragma unroll
      for (int tt=0;tt<4;tt++) bt[tt] = *(const bf16x8*)&t1_sh[tt*16+lr][ks*32 + lg*8];
      #pragma unroll
      for (int ct=0;ct<2;ct++)
        aw[ct] = *(const bf16x8*)(W1b + (size_t)(c*128 + w*32 + ct*16 + lr)*256 + ks*32 + lg*8);
      #pragma unroll
      for (int ct=0;ct<2;ct++)
        #pragma unroll
        for (int tt=0;tt<4;tt++)
          midv[ct][tt] = __builtin_amdgcn_mfma_f32_16x16x32_bf16(aw[ct], bt[tt], midv[ct][tt], 0,0,0);
    }
    __syncthreads();       // prior FFN2 reads of mid done
    #pragma unroll
    for (int ct=0;ct<2;ct++)
      #pragma unroll
      for (int tt=0;tt<4;tt++){
        uint2 p;
        p.x = pk2(fmaxf(midv[ct][tt][0],0.f), fmaxf(midv[ct][tt][1],0.f));
        p.y = pk2(fmaxf(midv[ct][tt][2],0.f), fmaxf(midv[ct][tt][3],0.f));
        *(uint2*)&mid_sh[tt*16+lr][w*32 + ct*16 + lg*4] = p;
      }
    __syncthreads();
    #pragma unroll
    for (int ks=0; ks<4; ks++){
      bf16x8 bm[4], aw2[4];
      #pragma unroll
      for (int tt=0;tt<4;tt++) bm[tt] = *(const bf16x8*)&mid_sh[tt*16+lr][ks*32 + lg*8];
      #pragma unroll
      for (int et=0;et<4;et++)
        aw2[et] = *(const bf16x8*)(W2b + (size_t)(cb+et*16+lr)*1024 + c*128 + ks*32 + lg*8);
      #pragma unroll
      for (int et=0;et<4;et++)
        #pragma unroll
        for (int tt=0;tt<4;tt++)
          outv[et][tt] = __builtin_amdgcn_mfma_f32_16x16x32_bf16(aw2[et], bm[tt], outv[et][tt], 0,0,0);
    }
  }

  // ---------- t2 = LN(t1 + ffn), delta, z_out, o ----------
  f32x4 b24[4];
  #pragma unroll
  for (int et=0;et<4;et++) b24[et] = *(const f32x4*)(b2 + cb + et*16 + lg*4);
  float sum2[4], ssq2[4];
  #pragma unroll
  for (int tt=0;tt<4;tt++){
    int tok = tt*16 + lr;
    float s = 0.f, sq = 0.f;
    #pragma unroll
    for (int et=0;et<4;et++){
      uint2 t1v = *(const uint2*)&t1_sh[tok][cb + et*16 + lg*4];
      #pragma unroll
      for (int r=0;r<4;r++){
        unsigned short hs = (unsigned short)((r&1) ? ((r<2?t1v.x:t1v.y)>>16) : ((r<2?t1v.x:t1v.y)&0xFFFF));
        float v = outv[et][tt][r] + b24[et][r] + b2f(hs);
        outv[et][tt][r] = v; s += v; sq += v*v;
      }
    }
    s  += __shfl_xor(s,16);  s  += __shfl_xor(s,32);
    sq += __shfl_xor(sq,16); sq += __shfl_xor(sq,32);
    sum2[tt] = s; ssq2[tt] = sq;
  }
  if (lane < 16){
    #pragma unroll
    for (int tt=0;tt<4;tt++){ redA[w][tt*16+lane] = sum2[tt]; redB[w][tt*16+lane] = ssq2[tt]; }
  }
  __syncthreads();   // B2

  float gate = 0.f;
  if (tid < 64){
    float gacc = bg[tid];
    const f32x4* wgr = (const f32x4*)(Wg + tid*64);
    #pragma unroll
    for (int j=0;j<16;j++){
      f32x4 wv = wgr[j];
      f32x4 zv = *(const f32x4*)(z_sh + j*4);
      gacc += wv[0]*zv[0] + wv[1]*zv[1] + wv[2]*zv[2] + wv[3]*zv[3];
    }
    gate = 1.f/(1.f + __expf(-gacc));
  }

  f32x4 g24[4], be24[4], wop4[4];
  #pragma unroll
  for (int et=0;et<4;et++){
    int e0_ = cb + et*16 + lg*4;
    g24[et]  = *(const f32x4*)(g2 + e0_);
    be24[et] = *(const f32x4*)(be2 + e0_);
    wop4[et] = *(const f32x4*)(Wop + e0_);
  }
  float dpart[4];
  #pragma unroll
  for (int tt=0;tt<4;tt++){
    int tok = tt*16 + lr;
    float s  = redA[0][tok] + redA[1][tok] + redA[2][tok] + redA[3][tok];
    float sq = redB[0][tok] + redB[1][tok] + redB[2][tok] + redB[3][tok];
    float m = s * (1.f/256.f);
    float rs = rsqrtf(sq*(1.f/256.f) - m*m + 1e-5f);
    float d = 0.f;
    #pragma unroll
    for (int et=0;et<4;et++)
      #pragma unroll
      for (int r=0;r<4;r++){
        float t2 = (outv[et][tt][r]-m)*rs*g24[et][r] + be24[et][r];
        d += t2*wop4[et][r];
      }
    d += __shfl_xor(d,16); d += __shfl_xor(d,32);
    dpart[tt] = d;
  }
  __syncthreads();   // N1: protect redA rewrite
  if (lane < 16){
    #pragma unroll
    for (int tt=0;tt<4;tt++) redA[w][tt*16+lane] = dpart[tt];
  }
  __syncthreads();   // D2
  if (tid < 64){
    float delta = redA[0][tid]+redA[1][tid]+redA[2][tid]+redA[3][tid] + bop[0];
    float zo = z_sh[tid] + gate*delta;
    out[49152 + (size_t)n*64 + tid] = zo;
    z_sh[tid] = zo;
  }
  __syncthreads();   // E2
  if (tid < 24){
    const float* ar = Amat + tid*64;
    float s = cvec[tid];
    #pragma unroll
    for (int j=0;j<64;j++) s += z_sh[j]*ar[j];
    out[(size_t)n*24 + tid] = s;
  }
}

extern "C" void kernel_launch(void* const* d_in, const int* in_sizes, int n_in,
                              void* d_out, int out_size, void* d_ws, size_t ws_size,
                              hipStream_t stream) {
  const float* x_cont = (const float*)d_in[0];
  const float* z0    = (const float*)d_in[1];
  const float* W_ih  = (const float*)d_in[2];
  const float* W_hh  = (const float*)d_in[3];
  const float* b_ih  = (const float*)d_in[4];
  const float* b_hh  = (const float*)d_in[5];
  const float* Uf    = (const float*)d_in[6];
  const float* Wfp   = (const float*)d_in[7];
  const float* bfp   = (const float*)d_in[8];
  const float* FE    = (const float*)d_in[9];
  const float* W_in  = (const float*)d_in[10];
  const float* b_in  = (const float*)d_in[11];
  const float* W_ao  = (const float*)d_in[12];
  const float* b_ao  = (const float*)d_in[13];
  const float* g1    = (const float*)d_in[14];
  const float* be1   = (const float*)d_in[15];
  const float* W1    = (const float*)d_in[16];
  const float* b1    = (const float*)d_in[17];
  const float* W2    = (const float*)d_in[18];
  const float* b2    = (const float*)d_in[19];
  const float* g2    = (const float*)d_in[20];
  const float* be2   = (const float*)d_in[21];
  const float* Wop   = (const float*)d_in[22];
  const float* bop   = (const float*)d_in[23];
  const float* Wg    = (const float*)d_in[24];
  const float* bg    = (const float*)d_in[25];
  const float* Amat  = (const float*)d_in[26];
  const float* cvec  = (const float*)d_in[27];
  float* out = (float*)d_out;
  char* ws = (char*)d_ws;

  float* z    = (float*)(ws + 0);         // 2048*64*4
  float* Qm   = (float*)(ws + 524288);
  float* Km   = (float*)(ws + 589824);
  float* Vm   = (float*)(ws + 655360);
  float* G    = (float*)(ws + 720896);    // 8*64*64*4
  float* U    = (float*)(ws + 851968);
  float* Wb   = (float*)(ws + 854016);
  float* S    = (float*)(ws + 856064);
  float* ab   = (float*)(ws + 856320);
  short* M2t  = (short*)(ws + 857344);    // 256*512*2
  short* W1b  = (short*)(ws + 1119488);   // 1024*256*2
  short* W2b  = (short*)(ws + 1643776);   // 256*1024*2

  hipLaunchKernelGGL(k_pre_qkv, dim3(192), dim3(256), 0, stream, FE, W_in, Qm, Km, Vm);
  hipLaunchKernelGGL(k_pre2, dim3(2710), dim3(256), 0, stream,
                     Qm, Km, Vm, b_in, W_ao, b_ao, G, U, Wb, S, ab, M2t,
                     W1, W2, W1b, W2b,
                     x_cont, z0, W_ih, W_hh, b_ih, b_hh, Uf, Wfp, bfp, z);
  hipLaunchKernelGGL(k_main, dim3(2048), dim3(256), 0, stream, z, G, U, Wb, S, ab, M2t, FE,
                     W1b, b1, W2b, b2, g1, be1, g2, be2, Wop, bop, Wg, bg, Amat, cvec, out);
}

// Round 5
// 507.984 us; speedup vs baseline: 1.5522x; 1.1715x over previous
//
#include <hip/hip_runtime.h>

typedef short bf16x8 __attribute__((ext_vector_type(8)));
typedef float f32x4  __attribute__((ext_vector_type(4)));

__device__ __forceinline__ unsigned short f2b(float f){
  union { float f; unsigned u; } v; v.f = f;
  unsigned r = v.u + 0x7FFFu + ((v.u >> 16) & 1u);
  return (unsigned short)(r >> 16);
}
__device__ __forceinline__ float b2f(unsigned short s){
  union { unsigned u; float f; } v; v.u = ((unsigned)s) << 16;
  return v.f;
}
// pack two f32 -> one u32 of 2x bf16 (RNE) in one VALU op
__device__ __forceinline__ unsigned pk2(float lo, float hi){
  unsigned r;
  asm("v_cvt_pk_bf16_f32 %0, %1, %2" : "=v"(r) : "v"(lo), "v"(hi));
  return r;
}

// ---------------- stage 1: Qm/Km/Vm = FE @ W_in^T  (3 x 64 x 256) ----------------
__global__ void k_pre_qkv(const float* __restrict__ FE, const float* __restrict__ W_in,
                          float* __restrict__ Qm, float* __restrict__ Km, float* __restrict__ Vm){
  int id = blockIdx.x*256 + threadIdx.x;      // 49152
  int part = id >> 14;
  int l = (id >> 8) & 63;
  int d = id & 255;
  const float4* fe = (const float4*)(FE + l*256);
  const float4* wr = (const float4*)(W_in + (part*256 + d)*256);
  float s = 0.f;
  #pragma unroll 8
  for (int k=0;k<64;k++){
    float4 a = fe[k], b = wr[k];
    s += a.x*b.x + a.y*b.y + a.z*b.z + a.w*b.w;
  }
  float* dst = (part==0)?Qm:((part==1)?Km:Vm);
  dst[l*256+d] = s;
}

// ---------------- stage 2 (merged): att-tables + M2t + weight cvt + RNN ----------------
__global__ void k_pre2(const float* __restrict__ Qm, const float* __restrict__ Km,
                       const float* __restrict__ Vm,
                       const float* __restrict__ b_in, const float* __restrict__ W_ao,
                       const float* __restrict__ b_ao,
                       float* __restrict__ G, float* __restrict__ U,
                       float* __restrict__ W, float* __restrict__ S,
                       float* __restrict__ abias, short* __restrict__ M2t,
                       const float* __restrict__ W1, const float* __restrict__ W2,
                       short* __restrict__ W1b, short* __restrict__ W2b,
                       const float* __restrict__ x_cont, const float* __restrict__ z0,
                       const float* __restrict__ W_ih, const float* __restrict__ W_hh,
                       const float* __restrict__ b_ih, const float* __restrict__ b_hh,
                       const float* __restrict__ Uf, const float* __restrict__ Wfp,
                       const float* __restrict__ bfp, float* __restrict__ zout){
  int bid = blockIdx.x;
  int tid = threadIdx.x;
  if (bid < 134){
    int id = bid*256 + tid;
    const float inv = 0.17677669529663687f;   // 1/sqrt(32)
    if (id < 32768){
      int h = id >> 12, lq = (id>>6)&63, lk = id&63;
      const float* qp = Qm + lq*256 + h*32;
      const float* kp = Km + lk*256 + h*32;
      float s=0.f;
      #pragma unroll
      for (int d=0;d<32;d++) s += qp[d]*kp[d];
      G[id] = s*inv;
    } else if (id < 33280){
      int j = id - 32768; int h = j>>6, lq = j&63;
      const float* qp = Qm + lq*256 + h*32;
      const float* bk = b_in + 256 + h*32;
      float s=0.f;
      #pragma unroll
      for (int d=0;d<32;d++) s += qp[d]*bk[d];
      U[j] = s*inv;
    } else if (id < 33792){
      int j = id - 33280; int h = j>>6, lk = j&63;
      const float* kp = Km + lk*256 + h*32;
      const float* bq = b_in + h*32;
      float s=0.f;
      #pragma unroll
      for (int d=0;d<32;d++) s += bq[d]*kp[d];
      W[j] = s*inv;
    } else if (id < 33800){
      int h = id - 33792;
      float s=0.f;
      #pragma unroll
      for (int d=0;d<32;d++) s += b_in[h*32+d]*b_in[256+h*32+d];
      S[h] = s*inv;
    } else if (id < 34056){
      int e = id - 33800;
      float s = b_ao[e];
      for (int d=0; d<256; d++) s += b_in[512+d]*W_ao[e*256+d];
      abias[e] = s;
    }
    return;
  }
  if (bid < 646){
    int id = (bid-134)*256 + tid;   // 131072 = 256*512
    int e = id >> 9, kk = id & 511;
    int h = kk >> 6, lk = kk & 63;
    const float* vp = Vm + lk*256 + h*32;
    const float* wp = W_ao + e*256 + h*32;
    float s=0.f;
    #pragma unroll
    for (int d=0;d<32;d++) s += vp[d]*wp[d];
    M2t[id] = (short)f2b(s);
    return;
  }
  if (bid < 2694){
    int id = (bid-646)*256 + tid;   // 524288
    if (id < 262144) W1b[id] = (short)f2b(W1[id]);
    else             W2b[id-262144] = (short)f2b(W2[id-262144]);
    return;
  }
  // ---- RNN: blocks 2694..2709, lanes 0..63 active ----
  {
    int b = bid - 2694;
    int l = tid;
    bool act = (l < 64);
    __shared__ float h_sh[64];
    __shared__ float fh_sh[24];
    __shared__ float WfpT[24][64];
    float wr[64];
    float wih=0, bb=0, bf=0;
    float uf0=0,uf1=0,uf2=0,uf3=0;
    if (act){
      #pragma unroll
      for (int j=0;j<64;j++) wr[j] = W_hh[l*64+j];
      #pragma unroll
      for (int j=0;j<24;j++) WfpT[j][l] = Wfp[l*24+j];
      wih = W_ih[l];
      bb  = b_ih[l] + b_hh[l];
      bf  = bfp[l];
      if (l < 24){ uf0=Uf[l*4+0]; uf1=Uf[l*4+1]; uf2=Uf[l*4+2]; uf3=Uf[l*4+3]; }
      h_sh[l] = z0[l];
    }
    __syncthreads();
    const float* xb = x_cont + (size_t)b*128*97;
    for (int t=0;t<128;t++){
      float hn = 0.f, fh = 0.f;
      if (act){
        float x0 = xb[t*97];
        float a0=0,a1=0,a2=0,a3=0;
        #pragma unroll
        for (int j=0;j<64;j+=4){
          a0 += wr[j  ]*h_sh[j  ];
          a1 += wr[j+1]*h_sh[j+1];
          a2 += wr[j+2]*h_sh[j+2];
          a3 += wr[j+3]*h_sh[j+3];
        }
        hn = fmaxf(x0*wih + bb + ((a0+a1)+(a2+a3)), 0.f);
        if (l < 24){
          const float* xf = xb + t*97 + 1 + l*4;
          fh = xf[0]*uf0 + xf[1]*uf1 + xf[2]*uf2 + xf[3]*uf3;
        }
      }
      __syncthreads();
      if (act){
        h_sh[l] = hn;
        if (l < 24) fh_sh[l] = fh;
      }
      __syncthreads();
      if (act){
        float zv = hn + bf;
        #pragma unroll
        for (int j=0;j<24;j++) zv += fh_sh[j]*WfpT[j][l];
        zout[((size_t)b*128 + t)*64 + l] = zv;
      }
    }
  }
}

// ---------------- fused per-token transformer block (2048 blocks x 256 thr) ----------------
// Transposed-acc: acc[et][tt] elem r -> (e = cb+et*16+lg*4+r, tok = tt*16+lr).
// Attention: each wave computes softmax only for its own row-quarter (tt==w),
// packs the MFMA B-fragment, publishes via pa_sh (writer/reader layouts identical),
// 1 barrier per head (double-buffered).
__global__ __launch_bounds__(256, 2) void k_main(
  const float* __restrict__ zall, const float* __restrict__ Gmat,
  const float* __restrict__ Ubuf, const float* __restrict__ Wbuf, const float* __restrict__ Sbuf,
  const float* __restrict__ abias, const short* __restrict__ M2t,
  const float* __restrict__ FE,
  const short* __restrict__ W1b, const float* __restrict__ b1,
  const short* __restrict__ W2b, const float* __restrict__ b2,
  const float* __restrict__ g1, const float* __restrict__ be1,
  const float* __restrict__ g2, const float* __restrict__ be2,
  const float* __restrict__ Wop, const float* __restrict__ bop,
  const float* __restrict__ Wg, const float* __restrict__ bg,
  const float* __restrict__ Amat, const float* __restrict__ cvec,
  float* __restrict__ out)
{
  const int n = blockIdx.x;
  const int tid = threadIdx.x;
  const int w = tid >> 6, lane = tid & 63, lg = lane >> 4, lr = lane & 15;
  const int cb = w * 64;

  __shared__ __align__(16) short t1_sh[64][264];   // 33792 B, stride 528B = 33*16 (16B aligned)
  __shared__ __align__(16) char  upool2[17408];    // union: mid[64][136] | pa[2][4][2][64][8]
  __shared__ float redA[4][64];                    // 1024
  __shared__ float redB[4][64];                    // 1024
  __shared__ float z_sh[64];                       // 256   -> total 53504 B

  short (*mid_sh)[136] = reinterpret_cast<short (*)[136]>(upool2);
  short (*pa_sh)[4][2][64][8] = reinterpret_cast<short (*)[4][2][64][8]>(upool2);

  if (tid < 64) z_sh[tid] = zall[n*64 + tid];
  __syncthreads();   // Z0

  // per-lane z slice for attention logits: zk[i] = z[lk], lk = (i>>3)*32 + lg*8 + (i&7)
  float zkf[16];
  #pragma unroll
  for (int i=0;i<16;i++) zkf[i] = z_sh[(i>>3)*32 + lg*8 + (i&7)];

  // ---------- attention: 1x softmax + pa exchange, 1 barrier/head ----------
  f32x4 acc[4][4];
  #pragma unroll
  for (int et=0;et<4;et++)
    #pragma unroll
    for (int tt=0;tt<4;tt++){ f32x4 zz = {0.f,0.f,0.f,0.f}; acc[et][tt] = zz; }

  const int lq_own = w*16 + lr;          // row this thread's softmax covers
  const float zq_own = z_sh[lq_own];

  #pragma unroll 1
  for (int h=0; h<8; ++h){
    // --- softmax for rows of quarter tt==w (16 logits/thread, 4 lanes per row) ---
    {
      const float sh = Sbuf[h];
      const float uh = Ubuf[h*64 + lq_own];
      const float* gp = Gmat + (size_t)(h*64+lq_own)*64;
      float e0[16];
      #pragma unroll
      for (int ks=0;ks<2;ks++){
        f32x4 ga = *(const f32x4*)(gp + ks*32 + lg*8);
        f32x4 gb = *(const f32x4*)(gp + ks*32 + lg*8 + 4);
        f32x4 wa = *(const f32x4*)(Wbuf + h*64 + ks*32 + lg*8);
        f32x4 wb = *(const f32x4*)(Wbuf + h*64 + ks*32 + lg*8 + 4);
        #pragma unroll
        for (int j=0;j<4;j++){
          float zk = zkf[ks*8+j];
          e0[ks*8+j]   = zq_own*(zk*ga[j] + uh) + (zk*wa[j] + sh);
          float zk2 = zkf[ks*8+4+j];
          e0[ks*8+4+j] = zq_own*(zk2*gb[j] + uh) + (zk2*wb[j] + sh);
        }
      }
      float mx = e0[0];
      #pragma unroll
      for (int i=1;i<16;i++) mx = fmaxf(mx, e0[i]);
      mx = fmaxf(mx, __shfl_xor(mx,16));
      mx = fmaxf(mx, __shfl_xor(mx,32));
      float sum = 0.f;
      #pragma unroll
      for (int i=0;i<16;i++){ e0[i] = __expf(e0[i]-mx); sum += e0[i]; }
      sum += __shfl_xor(sum,16);
      sum += __shfl_xor(sum,32);
      float inv = 1.f/sum;
      #pragma unroll
      for (int ks=0;ks<2;ks++){
        union { bf16x8 v; unsigned u[4]; } pa;
        #pragma unroll
        for (int p=0;p<4;p++)
          pa.u[p] = pk2(e0[ks*8+2*p]*inv*zkf[ks*8+2*p], e0[ks*8+2*p+1]*inv*zkf[ks*8+2*p+1]);
        *(bf16x8*)&pa_sh[h&1][w][ks][lane][0] = pa.v;
      }
    }
    __syncthreads();   // pa[h&1] ready; reads of h-2's buffer finished before barrier h-1
    // --- MFMA: acc[et][tt] += M2t-frag x pa-frag ---
    #pragma unroll
    for (int ks=0; ks<2; ks++){
      bf16x8 am[4], bt[4];
      #pragma unroll
      for (int et=0;et<4;et++)
        am[et] = *(const bf16x8*)(M2t + (size_t)(cb+et*16+lr)*512 + h*64 + ks*32 + lg*8);
      #pragma unroll
      for (int tt=0;tt<4;tt++) bt[tt] = *(const bf16x8*)&pa_sh[h&1][tt][ks][lane][0];
      #pragma unroll
      for (int et=0;et<4;et++)
        #pragma unroll
        for (int tt=0;tt<4;tt++)
          acc[et][tt] = __builtin_amdgcn_mfma_f32_16x16x32_bf16(am[et], bt[tt], acc[et][tt], 0,0,0);
    }
  }

  // ---------- t1 = LN(tokens + aop) ----------
  f32x4 ab4[4], g14[4], be14[4];
  #pragma unroll
  for (int et=0;et<4;et++){
    int e0_ = cb + et*16 + lg*4;
    ab4[et]  = *(const f32x4*)(abias + e0_);
    g14[et]  = *(const f32x4*)(g1 + e0_);
    be14[et] = *(const f32x4*)(be1 + e0_);
  }
  float sum1[4], ssq1[4];
  #pragma unroll
  for (int tt=0;tt<4;tt++){
    int tok = tt*16 + lr;
    float zt = z_sh[tok];
    float s = 0.f, sq = 0.f;
    #pragma unroll
    for (int et=0;et<4;et++){
      f32x4 fe = *(const f32x4*)(FE + (size_t)tok*256 + cb + et*16 + lg*4);
      #pragma unroll
      for (int r=0;r<4;r++){
        float v = acc[et][tt][r] + ab4[et][r] + zt*fe[r];
        acc[et][tt][r] = v; s += v; sq += v*v;
      }
    }
    s  += __shfl_xor(s,16);  s  += __shfl_xor(s,32);
    sq += __shfl_xor(sq,16); sq += __shfl_xor(sq,32);
    sum1[tt] = s; ssq1[tt] = sq;
  }
  if (lane < 16){
    #pragma unroll
    for (int tt=0;tt<4;tt++){ redA[w][tt*16+lane] = sum1[tt]; redB[w][tt*16+lane] = ssq1[tt]; }
  }
  __syncthreads();   // S1
  float mu1[4], rs1[4];
  #pragma unroll
  for (int tt=0;tt<4;tt++){
    int tok = tt*16 + lr;
    float s  = redA[0][tok] + redA[1][tok] + redA[2][tok] + redA[3][tok];
    float sq = redB[0][tok] + redB[1][tok] + redB[2][tok] + redB[3][tok];
    float m = s * (1.f/256.f);
    mu1[tt] = m;
    rs1[tt] = rsqrtf(sq*(1.f/256.f) - m*m + 1e-5f);
  }
  #pragma unroll
  for (int et=0;et<4;et++)
    #pragma unroll
    for (int tt=0;tt<4;tt++){
      uint2 p;
      float v0 = (acc[et][tt][0]-mu1[tt])*rs1[tt]*g14[et][0] + be14[et][0];
      float v1 = (acc[et][tt][1]-mu1[tt])*rs1[tt]*g14[et][1] + be14[et][1];
      float v2 = (acc[et][tt][2]-mu1[tt])*rs1[tt]*g14[et][2] + be14[et][2];
      float v3 = (acc[et][tt][3]-mu1[tt])*rs1[tt]*g14[et][3] + be14[et][3];
      p.x = pk2(v0,v1); p.y = pk2(v2,v3);
      *(uint2*)&t1_sh[tt*16+lr][cb + et*16 + lg*4] = p;
    }
  __syncthreads();   // T1: t1 ready (also: last pa reads done -> upool2 reusable as mid)

  // ---------- FFN: 8 chunks of 128 mid-channels ----------
  f32x4 outv[4][4];
  #pragma unroll
  for (int et=0;et<4;et++)
    #pragma unroll
    for (int tt=0;tt<4;tt++){ f32x4 zz = {0.f,0.f,0.f,0.f}; outv[et][tt] = zz; }

  #pragma unroll 1
  for (int c=0; c<8; c++){
    f32x4 midv[2][4];
    #pragma unroll
    for (int ct=0;ct<2;ct++){
      f32x4 bi = *(const f32x4*)(b1 + c*128 + w*32 + ct*16 + lg*4);
      #pragma unroll
      for (int tt=0;tt<4;tt++) midv[ct][tt] = bi;
    }
    #pragma unroll
    for (int ks=0; ks<8; ks++){
      bf16x8 bt[4], aw[2];
      #pragma unroll
      for (int tt=0;tt<4;tt++) bt[tt] = *(const bf16x8*)&t1_sh[tt*16+lr][ks*32 + lg*8];
      #pragma unroll
      for (int ct=0;ct<2;ct++)
        aw[ct] = *(const bf16x8*)(W1b + (size_t)(c*128 + w*32 + ct*16 + lr)*256 + ks*32 + lg*8);
      #pragma unroll
      for (int ct=0;ct<2;ct++)
        #pragma unroll
        for (int tt=0;tt<4;tt++)
          midv[ct][tt] = __builtin_amdgcn_mfma_f32_16x16x32_bf16(aw[ct], bt[tt], midv[ct][tt], 0,0,0);
    }
    __syncthreads();       // prior FFN2 reads of mid done
    #pragma unroll
    for (int ct=0;ct<2;ct++)
      #pragma unroll
      for (int tt=0;tt<4;tt++){
        uint2 p;
        p.x = pk2(fmaxf(midv[ct][tt][0],0.f), fmaxf(midv[ct][tt][1],0.f));
        p.y = pk2(fmaxf(midv[ct][tt][2],0.f), fmaxf(midv[ct][tt][3],0.f));
        *(uint2*)&mid_sh[tt*16+lr][w*32 + ct*16 + lg*4] = p;
      }
    __syncthreads();
    #pragma unroll
    for (int ks=0; ks<4; ks++){
      bf16x8 bm[4], aw2[4];
      #pragma unroll
      for (int tt=0;tt<4;tt++) bm[tt] = *(const bf16x8*)&mid_sh[tt*16+lr][ks*32 + lg*8];
      #pragma unroll
      for (int et=0;et<4;et++)
        aw2[et] = *(const bf16x8*)(W2b + (size_t)(cb+et*16+lr)*1024 + c*128 + ks*32 + lg*8);
      #pragma unroll
      for (int et=0;et<4;et++)
        #pragma unroll
        for (int tt=0;tt<4;tt++)
          outv[et][tt] = __builtin_amdgcn_mfma_f32_16x16x32_bf16(aw2[et], bm[tt], outv[et][tt], 0,0,0);
    }
  }

  // ---------- t2 = LN(t1 + ffn), delta, z_out, o ----------
  f32x4 b24[4];
  #pragma unroll
  for (int et=0;et<4;et++) b24[et] = *(const f32x4*)(b2 + cb + et*16 + lg*4);
  float sum2[4], ssq2[4];
  #pragma unroll
  for (int tt=0;tt<4;tt++){
    int tok = tt*16 + lr;
    float s = 0.f, sq = 0.f;
    #pragma unroll
    for (int et=0;et<4;et++){
      uint2 t1v = *(const uint2*)&t1_sh[tok][cb + et*16 + lg*4];
      #pragma unroll
      for (int r=0;r<4;r++){
        unsigned short hs = (unsigned short)((r&1) ? ((r<2?t1v.x:t1v.y)>>16) : ((r<2?t1v.x:t1v.y)&0xFFFF));
        float v = outv[et][tt][r] + b24[et][r] + b2f(hs);
        outv[et][tt][r] = v; s += v; sq += v*v;
      }
    }
    s  += __shfl_xor(s,16);  s  += __shfl_xor(s,32);
    sq += __shfl_xor(sq,16); sq += __shfl_xor(sq,32);
    sum2[tt] = s; ssq2[tt] = sq;
  }
  if (lane < 16){
    #pragma unroll
    for (int tt=0;tt<4;tt++){ redA[w][tt*16+lane] = sum2[tt]; redB[w][tt*16+lane] = ssq2[tt]; }
  }
  __syncthreads();   // B2

  float gate = 0.f;
  if (tid < 64){
    float gacc = bg[tid];
    const f32x4* wgr = (const f32x4*)(Wg + tid*64);
    #pragma unroll
    for (int j=0;j<16;j++){
      f32x4 wv = wgr[j];
      f32x4 zv = *(const f32x4*)(z_sh + j*4);
      gacc += wv[0]*zv[0] + wv[1]*zv[1] + wv[2]*zv[2] + wv[3]*zv[3];
    }
    gate = 1.f/(1.f + __expf(-gacc));
  }

  f32x4 g24[4], be24[4], wop4[4];
  #pragma unroll
  for (int et=0;et<4;et++){
    int e0_ = cb + et*16 + lg*4;
    g24[et]  = *(const f32x4*)(g2 + e0_);
    be24[et] = *(const f32x4*)(be2 + e0_);
    wop4[et] = *(const f32x4*)(Wop + e0_);
  }
  float dpart[4];
  #pragma unroll
  for (int tt=0;tt<4;tt++){
    int tok = tt*16 + lr;
    float s  = redA[0][tok] + redA[1][tok] + redA[2][tok] + redA[3][tok];
    float sq = redB[0][tok] + redB[1][tok] + redB[2][tok] + redB[3][tok];
    float m = s * (1.f/256.f);
    float rs = rsqrtf(sq*(1.f/256.f) - m*m + 1e-5f);
    float d = 0.f;
    #pragma unroll
    for (int et=0;et<4;et++)
      #pragma unroll
      for (int r=0;r<4;r++){
        float t2 = (outv[et][tt][r]-m)*rs*g24[et][r] + be24[et][r];
        d += t2*wop4[et][r];
      }
    d += __shfl_xor(d,16); d += __shfl_xor(d,32);
    dpart[tt] = d;
  }
  __syncthreads();   // N1: protect redA rewrite
  if (lane < 16){
    #pragma unroll
    for (int tt=0;tt<4;tt++) redA[w][tt*16+lane] = dpart[tt];
  }
  __syncthreads();   // D2
  if (tid < 64){
    float delta = redA[0][tid]+redA[1][tid]+redA[2][tid]+redA[3][tid] + bop[0];
    float zo = z_sh[tid] + gate*delta;
    out[49152 + (size_t)n*64 + tid] = zo;
    z_sh[tid] = zo;
  }
  __syncthreads();   // E2
  if (tid < 24){
    const float* ar = Amat + tid*64;
    float s = cvec[tid];
    #pragma unroll
    for (int j=0;j<64;j++) s += z_sh[j]*ar[j];
    out[(size_t)n*24 + tid] = s;
  }
}

extern "C" void kernel_launch(void* const* d_in, const int* in_sizes, int n_in,
                              void* d_out, int out_size, void* d_ws, size_t ws_size,
                              hipStream_t stream) {
  const float* x_cont = (const float*)d_in[0];
  const float* z0    = (const float*)d_in[1];
  const float* W_ih  = (const float*)d_in[2];
  const float* W_hh  = (const float*)d_in[3];
  const float* b_ih  = (const float*)d_in[4];
  const float* b_hh  = (const float*)d_in[5];
  const float* Uf    = (const float*)d_in[6];
  const float* Wfp   = (const float*)d_in[7];
  const float* bfp   = (const float*)d_in[8];
  const float* FE    = (const float*)d_in[9];
  const float* W_in  = (const float*)d_in[10];
  const float* b_in  = (const float*)d_in[11];
  const float* W_ao  = (const float*)d_in[12];
  const float* b_ao  = (const float*)d_in[13];
  const float* g1    = (const float*)d_in[14];
  const float* be1   = (const float*)d_in[15];
  const float* W1    = (const float*)d_in[16];
  const float* b1    = (const float*)d_in[17];
  const float* W2    = (const float*)d_in[18];
  const float* b2    = (const float*)d_in[19];
  const float* g2    = (const float*)d_in[20];
  const float* be2   = (const float*)d_in[21];
  const float* Wop   = (const float*)d_in[22];
  const float* bop   = (const float*)d_in[23];
  const float* Wg    = (const float*)d_in[24];
  const float* bg    = (const float*)d_in[25];
  const float* Amat  = (const float*)d_in[26];
  const float* cvec  = (const float*)d_in[27];
  float* out = (float*)d_out;
  char* ws = (char*)d_ws;

  float* z    = (float*)(ws + 0);         // 2048*64*4
  float* Qm   = (float*)(ws + 524288);
  float* Km   = (float*)(ws + 589824);
  float* Vm   = (float*)(ws + 655360);
  float* G    = (float*)(ws + 720896);    // 8*64*64*4
  float* U    = (float*)(ws + 851968);
  float* Wb   = (float*)(ws + 854016);
  float* S    = (float*)(ws + 856064);
  float* ab   = (float*)(ws + 856320);
  short* M2t  = (short*)(ws + 857344);    // 256*512*2
  short* W1b  = (short*)(ws + 1119488);   // 1024*256*2
  short* W2b  = (short*)(ws + 1643776);   // 256*1024*2

  hipLaunchKernelGGL(k_pre_qkv, dim3(192), dim3(256), 0, stream, FE, W_in, Qm, Km, Vm);
  hipLaunchKernelGGL(k_pre2, dim3(2710), dim3(256), 0, stream,
                     Qm, Km, Vm, b_in, W_ao, b_ao, G, U, Wb, S, ab, M2t,
                     W1, W2, W1b, W2b,
                     x_cont, z0, W_ih, W_hh, b_ih, b_hh, Uf, Wfp, bfp, z);
  hipLaunchKernelGGL(k_main, dim3(2048), dim3(256), 0, stream, z, G, U, Wb, S, ab, M2t, FE,
                     W1b, b1, W2b, b2, g1, be1, g2, be2, Wop, bop, Wg, bg, Amat, cvec, out);
}